// Round 3
// baseline (1973.264 us; speedup 1.0000x reference)
//
#include <hip/hip_runtime.h>

// Swin block, MI355X gfx950. Global I/O fp32 (per reference); internal GEMMs
// bf16 via v_mfma_f32_16x16x32_bf16 with fp32 accumulation.
// Pipeline per batch-slice:
//   K0 cvt_weights : qkv_w/proj_w/w1/w2 fp32 -> bf16 in ws (once per call)
//   K1 attn_fused  : x -> x2 = x + proj(attn(LN1(x)))   [block = 8x8 window]
//   K2 mlp1_fused  : x2 -> mh_c = gelu(LN2(x2) @ w1_c^T + b1_c)  (4 chunks)
//   K3 gemm_bt     : out = mh @ w2^T + b2 + x2          (K=768 single pass)

typedef short s8v __attribute__((ext_vector_type(8)));
typedef float f4v __attribute__((ext_vector_type(4)));
typedef unsigned short u16;

static __device__ __forceinline__ float b2f(u16 u) {
    unsigned int x = ((unsigned int)u) << 16;
    return __builtin_bit_cast(float, x);
}
static __device__ __forceinline__ u16 f2b(float f) {
    unsigned int u = __builtin_bit_cast(unsigned int, f);
    u = (u + 0x7FFF + ((u >> 16) & 1)) >> 16;   // RNE
    return (u16)u;
}
static __device__ __forceinline__ f4v mfma16(s8v a, s8v b, f4v c) {
    return __builtin_amdgcn_mfma_f32_16x16x32_bf16(a, b, c, 0, 0, 0);
}

#define HSP 200   // padded row for 192-wide LDS tiles

// sizes (elems) of the 4 weight matrices and their bf16 ws offsets
#define SZ_QKV  110592   // 576 x 192
#define SZ_PROJ  36864   // 192 x 192
#define SZ_W1   147456   // 768 x 192
#define SZ_W2   147456   // 192 x 768
#define OFF_PROJ (SZ_QKV)
#define OFF_W1   (SZ_QKV + SZ_PROJ)
#define OFF_W2   (SZ_QKV + SZ_PROJ + SZ_W1)
#define W_TOTAL  (SZ_QKV + SZ_PROJ + SZ_W1 + SZ_W2)   // 442368

// =============== K0: weight fp32 -> bf16 =====================================
__global__ __launch_bounds__(256) void cvt_weights(
    const float* __restrict__ qkv_w, const float* __restrict__ proj_w,
    const float* __restrict__ w1, const float* __restrict__ w2,
    u16* __restrict__ dst)
{
    int i4 = (blockIdx.x * 256 + threadIdx.x) * 4;
    const float* src; int off;
    if (i4 < OFF_PROJ)     { src = qkv_w; off = i4; }
    else if (i4 < OFF_W1)  { src = proj_w; off = i4 - OFF_PROJ; }
    else if (i4 < OFF_W2)  { src = w1; off = i4 - OFF_W1; }
    else                   { src = w2; off = i4 - OFF_W2; }
    float4 v = *(const float4*)(src + off);
    ushort4 o;
    o.x = f2b(v.x); o.y = f2b(v.y); o.z = f2b(v.z); o.w = f2b(v.w);
    *(ushort4*)(dst + i4) = o;
}

// =============== K1: fused LN1 + QKV + window-attention + proj + resid =======
__global__ __launch_bounds__(256) void attn_fused(
    const float* __restrict__ x, const u16* __restrict__ Wqkv,
    const float* __restrict__ bqkv, const u16* __restrict__ Wproj,
    const float* __restrict__ bproj, const float* __restrict__ g1,
    const float* __restrict__ bn1, u16* __restrict__ x2)
{
    __shared__ __align__(16) u16 lds[27904];   // 55808 B
    u16* hs   = lds;           // 64 x 200 (LN1'd tokens, bf16)
    u16* qs   = lds + 12800;   // 64 x 40
    u16* ks   = lds + 17920;   // 64 x 40
    u16* vt   = lds + 23040;   // 32 x 72  (v transposed: [dim][token])
    u16* pscr = lds + 25344;   // 4 waves x 16 x 40 (O transpose scratch)
    u16* ps   = lds + 12800;   // 64 x 72, aliases qs+ks (dead after S)

    const int tid = threadIdx.x;
    const int wv = tid >> 6, lane = tid & 63;
    const int lr = lane & 15, lq = lane >> 4;
    const int wloc = blockIdx.x;
    const int bb = wloc >> 8, wh = (wloc >> 4) & 15, ww = wloc & 15;

    // ---- stage hs with LN1 (roll(-4) gather), two-pass fp32 reads ----
    {
        int tk = tid >> 2, q4 = tid & 3;
        int gh = (wh * 8 + (tk >> 3) + 4) & 127;
        int gw = (ww * 8 + (tk & 7) + 4) & 127;
        const float* xr = x + (((size_t)bb * 128 + gh) * 128 + gw) * 192 + q4 * 48;
        u16* hr = hs + tk * HSP + q4 * 48;
        float s = 0.f, sq = 0.f;
#pragma unroll
        for (int i = 0; i < 12; i++) {
            float4 v = *(const float4*)(xr + i * 4);
            s += v.x + v.y + v.z + v.w;
            sq += v.x * v.x + v.y * v.y + v.z * v.z + v.w * v.w;
        }
        s += __shfl_xor(s, 1); sq += __shfl_xor(sq, 1);
        s += __shfl_xor(s, 2); sq += __shfl_xor(sq, 2);
        float mean = s * (1.0f / 192.0f);
        float var = sq * (1.0f / 192.0f) - mean * mean;
        float rstd = 1.0f / sqrtf(var + 1e-5f);
#pragma unroll
        for (int i = 0; i < 12; i += 2) {   // 8 elems per iter
            float4 a = *(const float4*)(xr + i * 4);
            float4 b = *(const float4*)(xr + i * 4 + 4);
            s8v ov;
            int col = q4 * 48 + i * 4;
            ov[0] = (short)f2b((a.x - mean) * rstd * g1[col + 0] + bn1[col + 0]);
            ov[1] = (short)f2b((a.y - mean) * rstd * g1[col + 1] + bn1[col + 1]);
            ov[2] = (short)f2b((a.z - mean) * rstd * g1[col + 2] + bn1[col + 2]);
            ov[3] = (short)f2b((a.w - mean) * rstd * g1[col + 3] + bn1[col + 3]);
            ov[4] = (short)f2b((b.x - mean) * rstd * g1[col + 4] + bn1[col + 4]);
            ov[5] = (short)f2b((b.y - mean) * rstd * g1[col + 5] + bn1[col + 5]);
            ov[6] = (short)f2b((b.z - mean) * rstd * g1[col + 6] + bn1[col + 6]);
            ov[7] = (short)f2b((b.w - mean) * rstd * g1[col + 7] + bn1[col + 7]);
            *(s8v*)(hr + i * 4) = ov;
        }
    }
    __syncthreads();

    f4v acc2[12] = {};   // proj accumulators (64 x 192 across 4 waves)

    for (int h = 0; h < 6; h++) {
        __syncthreads();   // prior head's vt/ps readers done before overwrite

        // ---- qkv minigemm: 64 tokens x [q32|k32|v32] of head h, K=192 ----
        f4v acc[6] = {};
        for (int k0 = 0; k0 < 192; k0 += 32) {
            s8v af = *(const s8v*)&hs[(16 * wv + lr) * HSP + k0 + lq * 8];
#pragma unroll
            for (int n = 0; n < 6; n++) {
                int wr = (n < 2) ? (32 * h + 16 * n + lr)
                       : (n < 4) ? (192 + 32 * h + 16 * (n - 2) + lr)
                                 : (384 + 32 * h + 16 * (n - 4) + lr);
                s8v bf = *(const s8v*)&Wqkv[(size_t)wr * 192 + k0 + lq * 8];
                acc[n] = mfma16(af, bf, acc[n]);
            }
        }
        float bq0 = bqkv[32 * h + lr],       bq1 = bqkv[32 * h + 16 + lr];
        float bk0 = bqkv[192 + 32 * h + lr], bk1 = bqkv[192 + 32 * h + 16 + lr];
        float bv0 = bqkv[384 + 32 * h + lr], bv1 = bqkv[384 + 32 * h + 16 + lr];

        // ---- l2norm q,k -> qs/ks; v -> vt transposed ----
#pragma unroll
        for (int reg = 0; reg < 4; reg++) {
            int row = 16 * wv + lq * 4 + reg;
            float q0 = acc[0][reg] + bq0, q1 = acc[1][reg] + bq1;
            float ss = q0 * q0 + q1 * q1;
#pragma unroll
            for (int m = 1; m < 16; m <<= 1) ss += __shfl_xor(ss, m);
            float inv = 1.0f / fmaxf(sqrtf(ss), 1e-12f);
            qs[row * 40 + lr]      = f2b(q0 * inv);
            qs[row * 40 + 16 + lr] = f2b(q1 * inv);

            float k0v = acc[2][reg] + bk0, k1v = acc[3][reg] + bk1;
            ss = k0v * k0v + k1v * k1v;
#pragma unroll
            for (int m = 1; m < 16; m <<= 1) ss += __shfl_xor(ss, m);
            inv = 1.0f / fmaxf(sqrtf(ss), 1e-12f);
            ks[row * 40 + lr]      = f2b(k0v * inv);
            ks[row * 40 + 16 + lr] = f2b(k1v * inv);

            vt[lr * 72 + row]        = f2b(acc[4][reg] + bv0);
            vt[(16 + lr) * 72 + row] = f2b(acc[5][reg] + bv1);
        }
        __syncthreads();   // qs/ks/vt visible to all waves

        // ---- S = q k^T (64x64, K=32); wave owns rows [16wv,16wv+16) ----
        f4v accS[4] = {};
        {
            s8v aq = *(const s8v*)&qs[(16 * wv + lr) * 40 + lq * 8];
#pragma unroll
            for (int j = 0; j < 4; j++) {
                s8v bk = *(const s8v*)&ks[(16 * j + lr) * 40 + lq * 8];
                accS[j] = mfma16(aq, bk, accS[j]);
            }
        }
        __syncthreads();   // all waves done reading qs/ks before ps overwrite

        // ---- softmax + clip -> ps (wave-private rows) ----
        const float scale = 0.17677669529663687f;   // 32^-0.5
#pragma unroll
        for (int reg = 0; reg < 4; reg++) {
            int row = 16 * wv + lq * 4 + reg;
            float v0 = accS[0][reg] * scale, v1 = accS[1][reg] * scale;
            float v2 = accS[2][reg] * scale, v3 = accS[3][reg] * scale;
            float mx = fmaxf(fmaxf(v0, v1), fmaxf(v2, v3));
#pragma unroll
            for (int m = 1; m < 16; m <<= 1) mx = fmaxf(mx, __shfl_xor(mx, m));
            float e0 = expf(v0 - mx), e1 = expf(v1 - mx);
            float e2 = expf(v2 - mx), e3 = expf(v3 - mx);
            float sum = e0 + e1 + e2 + e3;
#pragma unroll
            for (int m = 1; m < 16; m <<= 1) sum += __shfl_xor(sum, m);
            float is = 1.0f / sum;
            ps[row * 72 +  0 + lr] = f2b(fminf(fmaxf(e0 * is, 1e-6f), 1.0f));
            ps[row * 72 + 16 + lr] = f2b(fminf(fmaxf(e1 * is, 1e-6f), 1.0f));
            ps[row * 72 + 32 + lr] = f2b(fminf(fmaxf(e2 * is, 1e-6f), 1.0f));
            ps[row * 72 + 48 + lr] = f2b(fminf(fmaxf(e3 * is, 1e-6f), 1.0f));
        }

        // ---- O = P V (16x32 per wave, K=64) ----
        f4v accO[2] = {};
#pragma unroll
        for (int kt = 0; kt < 2; kt++) {
            s8v ap = *(const s8v*)&ps[(16 * wv + lr) * 72 + 32 * kt + lq * 8];
#pragma unroll
            for (int n = 0; n < 2; n++) {
                s8v bvf = *(const s8v*)&vt[(16 * n + lr) * 72 + 32 * kt + lq * 8];
                accO[n] = mfma16(ap, bvf, accO[n]);
            }
        }

        // ---- transpose O via wave-private scratch; accumulate proj ----
        u16* pw = pscr + wv * 640;
#pragma unroll
        for (int n = 0; n < 2; n++)
#pragma unroll
            for (int reg = 0; reg < 4; reg++)
                pw[(lq * 4 + reg) * 40 + 16 * n + lr] = f2b(accO[n][reg]);
        s8v apj = *(const s8v*)&pw[lr * 40 + lq * 8];
#pragma unroll
        for (int n = 0; n < 12; n++) {
            s8v bpj = *(const s8v*)&Wproj[(size_t)(16 * n + lr) * 192 + 32 * h + lq * 8];
            acc2[n] = mfma16(apj, bpj, acc2[n]);
        }
    }

    // ---- epilogue: x2 = proj + bias + x (scatter through roll(+4)) ----
#pragma unroll
    for (int reg = 0; reg < 4; reg++) {
        int tk = 16 * wv + lq * 4 + reg;
        int gh = (wh * 8 + (tk >> 3) + 4) & 127;
        int gw = (ww * 8 + (tk & 7) + 4) & 127;
        size_t base = (((size_t)bb * 128 + gh) * 128 + gw) * 192;
#pragma unroll
        for (int n = 0; n < 12; n++) {
            int col = 16 * n + lr;
            float v = acc2[n][reg] + bproj[col] + x[base + col];
            x2[base + col] = f2b(v);
        }
    }
}

// =============== K2: MLP GEMM1 with fused LN2 + gelu =========================
__global__ __launch_bounds__(256) void mlp1_fused(
    const u16* __restrict__ x2, const u16* __restrict__ W1,
    const float* __restrict__ B1, const float* __restrict__ g2,
    const float* __restrict__ bn2, u16* __restrict__ mh, int ldm)
{
    __shared__ __align__(16) u16 As[128 * HSP];   // 51200 B
    const int tid = threadIdx.x;
    const int wv = tid >> 6, lane = tid & 63;
    const int lr = lane & 15, lq = lane >> 4;
    const size_t m0 = (size_t)blockIdx.x * 128;

    {   // LN2 staging: x2 bf16 -> stats fp32 -> normalized bf16 in As
        int r = tid >> 1, hf = tid & 1;
        const u16* xr = x2 + (m0 + r) * 192 + hf * 96;
        u16* ar = As + r * HSP + hf * 96;
        float s = 0.f, sq = 0.f;
#pragma unroll
        for (int i = 0; i < 12; i++) {
            s8v v = *(const s8v*)(xr + i * 8);
#pragma unroll
            for (int j = 0; j < 8; j++) { float f = b2f((u16)v[j]); s += f; sq += f * f; }
        }
        s += __shfl_xor(s, 1); sq += __shfl_xor(sq, 1);
        float mean = s * (1.0f / 192.0f);
        float var = sq * (1.0f / 192.0f) - mean * mean;
        float rstd = 1.0f / sqrtf(var + 1e-5f);
#pragma unroll
        for (int i = 0; i < 12; i++) {
            s8v v = *(const s8v*)(xr + i * 8);
            s8v ov;
#pragma unroll
            for (int j = 0; j < 8; j++) {
                int col = hf * 96 + i * 8 + j;
                ov[j] = (short)f2b((b2f((u16)v[j]) - mean) * rstd * g2[col] + bn2[col]);
            }
            *(s8v*)(ar + i * 8) = ov;
        }
    }
    __syncthreads();

    f4v acc[2][12] = {};   // wave rows [32wv, 32wv+32)
    for (int k0 = 0; k0 < 192; k0 += 32) {
        s8v af[2];
#pragma unroll
        for (int mt = 0; mt < 2; mt++)
            af[mt] = *(const s8v*)&As[(32 * wv + 16 * mt + lr) * HSP + k0 + lq * 8];
#pragma unroll
        for (int n = 0; n < 12; n++) {
            s8v bf = *(const s8v*)&W1[(size_t)(16 * n + lr) * 192 + k0 + lq * 8];
#pragma unroll
            for (int mt = 0; mt < 2; mt++)
                acc[mt][n] = mfma16(af[mt], bf, acc[mt][n]);
        }
    }

#pragma unroll
    for (int n = 0; n < 12; n++) {
        int col = 16 * n + lr;
        float bb = B1[col];
#pragma unroll
        for (int mt = 0; mt < 2; mt++)
#pragma unroll
            for (int reg = 0; reg < 4; reg++) {
                size_t row = m0 + 32 * wv + 16 * mt + lq * 4 + reg;
                float v = acc[mt][n][reg] + bb;
                v = 0.5f * v * (1.0f + erff(v * 0.70710678118654752f));
                mh[row * ldm + col] = f2b(v);
            }
    }
}

// =============== K3: GEMM C = A @ W^T (+bias)(+resid), out fp32 ==============
// RES: 0 none, 1 resid bf16, 2 resid fp32
#define BM 128
#define BN 64
#define LDT 40

template <int RES>
__global__ __launch_bounds__(256) void gemm_bt(
    const u16* __restrict__ A, int lda,
    const u16* __restrict__ W, int ldb,
    const float* __restrict__ bias,
    const u16* __restrict__ residB, const float* __restrict__ residF, int ldr,
    float* __restrict__ Cout, int ldc, int K)
{
    __shared__ __align__(16) u16 As[BM * LDT];
    __shared__ __align__(16) u16 Bs[BN * LDT];
    const int tid = threadIdx.x;
    const int wave = tid >> 6, lane = tid & 63;
    const int lr = lane & 15, lq = lane >> 4;
    const int wm = (wave >> 1) * 64;
    const int wn = (wave & 1) * 32;
    const size_t m0 = (size_t)blockIdx.y * BM;
    const int n0 = blockIdx.x * BN;

    const int ar = tid >> 1, ac = (tid & 1) * 16;
    const int br = tid >> 2, bc = (tid & 3) * 8;
    const u16* aptr = A + (m0 + ar) * (size_t)lda + ac;
    const u16* bptr = W + (size_t)(n0 + br) * ldb + bc;

    f4v acc[4][2] = {};
    for (int k0 = 0; k0 < K; k0 += 32) {
        __syncthreads();
        *(s8v*)&As[ar * LDT + ac]     = *(const s8v*)(aptr + k0);
        *(s8v*)&As[ar * LDT + ac + 8] = *(const s8v*)(aptr + k0 + 8);
        *(s8v*)&Bs[br * LDT + bc]     = *(const s8v*)(bptr + k0);
        __syncthreads();
        s8v af[4], bfr[2];
#pragma unroll
        for (int mt = 0; mt < 4; mt++)
            af[mt] = *(const s8v*)&As[(wm + mt * 16 + lr) * LDT + lq * 8];
#pragma unroll
        for (int nt = 0; nt < 2; nt++)
            bfr[nt] = *(const s8v*)&Bs[(wn + nt * 16 + lr) * LDT + lq * 8];
#pragma unroll
        for (int mt = 0; mt < 4; mt++)
#pragma unroll
            for (int nt = 0; nt < 2; nt++)
                acc[mt][nt] = mfma16(af[mt], bfr[nt], acc[mt][nt]);
    }

    float bv[2];
#pragma unroll
    for (int nt = 0; nt < 2; nt++) {
        int col = n0 + wn + nt * 16 + lr;
        bv[nt] = bias ? bias[col] : 0.0f;
    }
#pragma unroll
    for (int mt = 0; mt < 4; mt++)
#pragma unroll
        for (int reg = 0; reg < 4; reg++) {
            size_t row = m0 + wm + mt * 16 + lq * 4 + reg;
#pragma unroll
            for (int nt = 0; nt < 2; nt++) {
                int col = n0 + wn + nt * 16 + lr;
                float v = acc[mt][nt][reg] + bv[nt];
                if (RES == 1) v += b2f(residB[row * (size_t)ldr + col]);
                if (RES == 2) v += residF[row * (size_t)ldr + col];
                Cout[row * (size_t)ldc + col] = v;
            }
        }
}

// ---------------- driver -----------------------------------------------------
extern "C" void kernel_launch(void* const* d_in, const int* in_sizes, int n_in,
                              void* d_out, int out_size, void* d_ws, size_t ws_size,
                              hipStream_t stream) {
    const float* x      = (const float*)d_in[0];
    const float* qkv_w  = (const float*)d_in[1];
    const float* qkv_b  = (const float*)d_in[2];
    const float* proj_w = (const float*)d_in[3];
    const float* proj_b = (const float*)d_in[4];
    const float* n1_g   = (const float*)d_in[5];
    const float* n1_b   = (const float*)d_in[6];
    const float* n2_g   = (const float*)d_in[7];
    const float* n2_b   = (const float*)d_in[8];
    const float* w1     = (const float*)d_in[9];
    const float* b1     = (const float*)d_in[10];
    const float* w2     = (const float*)d_in[11];
    const float* b2     = (const float*)d_in[12];
    float* out = (float*)d_out;

    u16* wsu = (u16*)d_ws;
    u16* wQ  = wsu;
    u16* wP  = wsu + OFF_PROJ;
    u16* wW1 = wsu + OFF_W1;
    u16* wW2 = wsu + OFF_W2;
    char* dataBase = (char*)d_ws + (1 << 20);
    size_t avail = (ws_size > (1 << 20)) ? ws_size - (1 << 20) : 0;

    dim3 blk(256);
    cvt_weights<<<W_TOTAL / 1024, blk, 0, stream>>>(qkv_w, proj_w, w1, w2, wsu);

    // pick largest batch-slice Bs with x2 (Ts x 192) + mh (Ts x 768) bf16 in ws
    int Bs = 16;
    while (Bs > 1 && (size_t)Bs * 16384 * (192 + 768) * 2 > avail) Bs >>= 1;
    const bool bigHC = ((size_t)Bs * 16384 * (192 + 768) * 2 <= avail);

    if (bigHC) {
        const int nslice = 16 / Bs;
        const size_t stok = (size_t)Bs * 16384;
        u16* x2buf = (u16*)dataBase;
        u16* mhbuf = x2buf + stok * 192;
        for (int s = 0; s < nslice; s++) {
            const float* xs = x + (size_t)s * stok * 192;
            float* outs = out + (size_t)s * stok * 192;
            attn_fused<<<Bs * 256, blk, 0, stream>>>(xs, wQ, qkv_b, wP, proj_b,
                                                     n1_g, n1_b, x2buf);
            for (int c = 0; c < 4; c++)
                mlp1_fused<<<Bs * 128, blk, 0, stream>>>(
                    x2buf, wW1 + (size_t)c * 192 * 192, b1 + c * 192,
                    n2_g, n2_b, mhbuf + c * 192, 768);
            gemm_bt<1><<<dim3(3, Bs * 128), blk, 0, stream>>>(
                mhbuf, 768, wW2, 768, b2, x2buf, nullptr, 192, outs, 192, 768);
        }
    } else {
        // tiny-ws fallback: Bs=1, hidden chunked at 192, out accumulated fp32
        const size_t stok = 16384;
        u16* x2buf = (u16*)dataBase;
        u16* mhbuf = x2buf + stok * 192;
        for (int s = 0; s < 16; s++) {
            const float* xs = x + (size_t)s * stok * 192;
            float* outs = out + (size_t)s * stok * 192;
            attn_fused<<<256, blk, 0, stream>>>(xs, wQ, qkv_b, wP, proj_b,
                                                n1_g, n1_b, x2buf);
            for (int c = 0; c < 4; c++) {
                mlp1_fused<<<128, blk, 0, stream>>>(
                    x2buf, wW1 + (size_t)c * 192 * 192, b1 + c * 192,
                    n2_g, n2_b, mhbuf, 192);
                if (c == 0)
                    gemm_bt<1><<<dim3(3, 128), blk, 0, stream>>>(
                        mhbuf, 192, wW2 + c * 192, 768, b2,
                        x2buf, nullptr, 192, outs, 192, 192);
                else
                    gemm_bt<2><<<dim3(3, 128), blk, 0, stream>>>(
                        mhbuf, 192, wW2 + c * 192, 768, nullptr,
                        nullptr, outs, 192, outs, 192, 192);
            }
        }
    }
}